// Round 1
// 182.252 us; speedup vs baseline: 1.0063x; 1.0063x over previous
//
#include <hip/hip_runtime.h>

#define PI2 6.28318530717958647692f

// ===========================================================================
// Kernel 1: per (b,t) plane forward DFT restricted to kept modes.
// Phase 1: A2[kx][w] = sum_h X[h][w] e^{-2pi i kx h/128}, radix-2 fold over h.
//   Twiddle table stores only kx=1..16 (8 KB); kxi>=16 (kx=112..127) uses
//   conjugate symmetry: tw(112+r) = conj(tw(16-r)). kx=0 is the DC term.
// Phase 2: Xf[kx][ky] = sum_w A2[kx][w] e^{-2pi i ky w/128}, fold over w.
//   E2 table is rebuilt into the same 8 KB buffer after phase 1.
// A2t layout: f2 index = w*32 + (kxi ^ (w&30))  (XOR swizzle, no pad).
// LDS total = 32768 + 8192 = 40960 B -> exactly 4 blocks/CU (grid = 4/CU).
// Xf layout: [plane][kxi][ky][ri] (1024 dwords/plane). Scale 1/16384.
// ===========================================================================
__global__ __launch_bounds__(256, 4) void k_fwd(const float* __restrict__ X,
                                                float* __restrict__ Xf) {
  __shared__ __attribute__((aligned(16))) float A2t[128 * 32 * 2];  // 32 KB
  __shared__ __attribute__((aligned(16))) float Tt[64 * 16 * 2];    // 8 KB
  const int plane = blockIdx.x;
  const int tid = threadIdx.x;
  const float* Xp = X + (size_t)plane * (128 * 128);

  // ---- E1 table: Tt[h][k] = e^{-2pi i (k+1) h / 128}, h<64, k<16 ----
  #pragma unroll
  for (int k = 0; k < 4; ++k) {
    int idx = tid + k * 256;              // 1024 entries
    int h = idx >> 4, kx = (idx & 15) + 1;
    float ang = -PI2 * (float)((kx * h) & 127) / 128.f;
    float s_, c_;
    __sincosf(ang, &s_, &c_);
    Tt[idx * 2] = c_; Tt[idx * 2 + 1] = s_;
  }
  __syncthreads();

  // ---- phase 1: thread = (w 0..127, kxg 0..1), 16 kxi each ----
  {
    const int w = tid & 127;
    const int kxg = tid >> 7;
    const int swz = w & 30;
    float cr[16], ci[16];
    #pragma unroll
    for (int j = 0; j < 16; ++j) { cr[j] = 0.f; ci[j] = 0.f; }
    float x0 = Xp[w], x1 = Xp[64 * 128 + w];
    if (kxg == 0) {
      // kxi = 0..15, kx = kxi. Even kx -> ue, odd kx -> uo.
      for (int h = 0; h < 64; ++h) {
        float nx0 = 0.f, nx1 = 0.f;
        if (h < 63) { nx0 = Xp[(h + 1) * 128 + w]; nx1 = Xp[(h + 65) * 128 + w]; }
        float ue = x0 + x1, uo = x0 - x1;
        const float4* Trow = (const float4*)&Tt[h * 32];
        cr[0] += ue;                              // kx = 0: twiddle = 1
        #pragma unroll
        for (int m = 0; m < 7; ++m) {
          float4 e = Trow[m];                     // (c,s) for kx=2m+1, 2m+2
          cr[2 * m + 1] = fmaf(uo, e.x, cr[2 * m + 1]);
          ci[2 * m + 1] = fmaf(uo, e.y, ci[2 * m + 1]);
          cr[2 * m + 2] = fmaf(ue, e.z, cr[2 * m + 2]);
          ci[2 * m + 2] = fmaf(ue, e.w, ci[2 * m + 2]);
        }
        { float4 e = Trow[7];                     // (c15,s15,c16,s16)
          cr[15] = fmaf(uo, e.x, cr[15]);
          ci[15] = fmaf(uo, e.y, ci[15]); }
        x0 = nx0; x1 = nx1;
      }
    } else {
      // kxi = 16+r, kx = 112+r: tw = conj(tw(16-r)); parity(kx) = parity(r).
      for (int h = 0; h < 64; ++h) {
        float nx0 = 0.f, nx1 = 0.f;
        if (h < 63) { nx0 = Xp[(h + 1) * 128 + w]; nx1 = Xp[(h + 65) * 128 + w]; }
        float ue = x0 + x1, uo = x0 - x1;
        const float4* Trow = (const float4*)&Tt[h * 32];
        #pragma unroll
        for (int m = 0; m < 7; ++m) {
          float4 e = Trow[m];                     // kx'=2m+1 -> r=15-2m ; kx'=2m+2 -> r=14-2m
          cr[15 - 2 * m] = fmaf(uo, e.x, cr[15 - 2 * m]);
          ci[15 - 2 * m] = fmaf(-uo, e.y, ci[15 - 2 * m]);
          cr[14 - 2 * m] = fmaf(ue, e.z, cr[14 - 2 * m]);
          ci[14 - 2 * m] = fmaf(-ue, e.w, ci[14 - 2 * m]);
        }
        { float4 e = Trow[7];                     // kx'=15 -> r=1 ; kx'=16 -> r=0
          cr[1] = fmaf(uo, e.x, cr[1]); ci[1] = fmaf(-uo, e.y, ci[1]);
          cr[0] = fmaf(ue, e.z, cr[0]); ci[0] = fmaf(-ue, e.w, ci[0]); }
        x0 = nx0; x1 = nx1;
      }
    }
    #pragma unroll
    for (int j = 0; j < 16; ++j) {
      int f2i = w * 32 + ((kxg * 16 + j) ^ swz);
      *(float2*)&A2t[f2i * 2] = make_float2(cr[j], ci[j]);
    }
  }
  __syncthreads();

  // ---- E2 table rebuild into Tt: Tt[w][ky] = e^{-2pi i ky w /128}, w<64 ----
  #pragma unroll
  for (int k = 0; k < 4; ++k) {
    int idx = tid + k * 256;              // 1024 entries
    int w_ = idx >> 4, ky = idx & 15;
    float ang = -PI2 * (float)((ky * w_) & 127) / 128.f;
    float s_, c_;
    __sincosf(ang, &s_, &c_);
    Tt[idx * 2] = c_; Tt[idx * 2 + 1] = s_;
  }
  __syncthreads();

  // ---- phase 2: thread = (kxi 0..31, t 0..7); ky = {t, t+8} ----
  {
    const int kxi = tid >> 3;
    const int t = tid & 7;
    const float s = (t & 1) ? -1.f : 1.f;   // (-1)^ky, same for t and t+8
    float r0 = 0.f, i0 = 0.f, r1 = 0.f, i1 = 0.f;
    for (int w = 0; w < 64; ++w) {
      const int col = kxi ^ (w & 30);       // (w+64)&30 == w&30
      const float2 a = *(const float2*)&A2t[(w * 32 + col) * 2];
      const float2 b = *(const float2*)&A2t[((w + 64) * 32 + col) * 2];
      float ur = fmaf(s, b.x, a.x);
      float ui = fmaf(s, b.y, a.y);
      const float2 e0 = *(const float2*)&Tt[(w * 16 + t) * 2];
      const float2 e1 = *(const float2*)&Tt[(w * 16 + t + 8) * 2];
      r0 = fmaf(ur, e0.x, r0); r0 = fmaf(-ui, e0.y, r0);
      i0 = fmaf(ur, e0.y, i0); i0 = fmaf(ui, e0.x, i0);
      r1 = fmaf(ur, e1.x, r1); r1 = fmaf(-ui, e1.y, r1);
      i1 = fmaf(ur, e1.y, i1); i1 = fmaf(ui, e1.x, i1);
    }
    const float sc = 1.f / 16384.f;
    float* base = Xf + (size_t)plane * 1024 + kxi * 32;
    *(float2*)&base[t * 2]       = make_float2(r0 * sc, i0 * sc);
    *(float2*)&base[(t + 8) * 2] = make_float2(r1 * sc, i1 * sc);
  }
}

// ===========================================================================
// Kernel 2: channel mix. block = (corner 2, x 16, cg 32), c-tile of 2.
// grid 1024 (was 512): 4 blocks/CU co-resident, LDS 16 KB.
// thread = (b 16, y 16). Y[b][c][kxi][ky][ri], same layout as Xf.
// ===========================================================================
__global__ __launch_bounds__(256, 4) void k_mix(const float* __restrict__ Xf,
                                                const float* __restrict__ w0r,
                                                const float* __restrict__ w0i,
                                                const float* __restrict__ w1r,
                                                const float* __restrict__ w1i,
                                                float* __restrict__ Y) {
  __shared__ __attribute__((aligned(16))) float Wl[2 * 64 * 16 * 2]; // [c][t][y] f2
  const int bid = blockIdx.x;               // 0..1023
  const int c2 = bid >> 9;
  const int x  = (bid >> 5) & 15;
  const int cg = bid & 31;
  const int c0 = cg * 2;
  const int kxi = c2 * 16 + x;
  const float* Wr_g = c2 ? w1r : w0r;
  const float* Wi_g = c2 ? w1i : w0i;
  const int tid = threadIdx.x;
  const int b = tid >> 4;
  const int y = tid & 15;

  // stage weights: 2048 complex elements, coalesced (y fastest, 64B runs)
  #pragma unroll
  for (int k = 0; k < 8; ++k) {
    int idx = tid + k * 256;                // 0..2047
    int y_ = idx & 15, t_ = (idx >> 4) & 63, c_ = idx >> 10;
    size_t ga = (((size_t)(c0 + c_) * 64 + t_) * 16 + x) * 16 + y_;
    float wr = Wr_g[ga], wi = Wi_g[ga];
    Wl[idx * 2] = wr; Wl[idx * 2 + 1] = wi;
  }
  __syncthreads();

  float aR[2] = {}, aI[2] = {};
  const float* xbase = Xf + ((size_t)b * 64) * 1024 + kxi * 32 + y * 2;
  for (int t4 = 0; t4 < 64; t4 += 4) {
    float2 xv[4];
    #pragma unroll
    for (int q = 0; q < 4; ++q)
      xv[q] = *(const float2*)&xbase[(size_t)(t4 + q) * 1024];
    #pragma unroll
    for (int q = 0; q < 4; ++q) {
      int t = t4 + q;
      #pragma unroll
      for (int cj = 0; cj < 2; ++cj) {
        const float2 wv = *(const float2*)&Wl[((cj * 64 + t) * 16 + y) * 2];
        aR[cj] = fmaf(xv[q].x, wv.x, aR[cj]);
        aR[cj] = fmaf(-xv[q].y, wv.y, aR[cj]);
        aI[cj] = fmaf(xv[q].x, wv.y, aI[cj]);
        aI[cj] = fmaf(xv[q].y, wv.x, aI[cj]);
      }
    }
  }
  #pragma unroll
  for (int cj = 0; cj < 2; ++cj) {
    size_t ya = ((size_t)(b * 64 + c0 + cj)) * 1024 + kxi * 32 + y * 2;
    *(float2*)&Y[ya] = make_float2(aR[cj], aI[cj]);
  }
}

// ===========================================================================
// Kernel 3: per (b,c) plane inverse.
// Phase A: Z[h][ky] = sum_kxi Y[kxi][ky] e^{+2pi i kx h/128}; store
//          Mt[ky][h] = (f*Zr, -f*Zi), f = (ky==0)?1:2.  [ky][h] transpose:
//          writes are lane-consecutive (conflict-free), reads stay broadcast.
// Phase B: out[h][w] = sum_ky Mc*cos(2pi ky w/128) + Ms*sin(...),
//          folded over w / w+64 via ky parity.
// ===========================================================================
__global__ __launch_bounds__(256, 4) void k_inv(const float* __restrict__ Y,
                                                float* __restrict__ out) {
  __shared__ __attribute__((aligned(16))) float Yl[1024];
  __shared__ __attribute__((aligned(16))) float Mt[16 * 128 * 2];  // [ky][h] f2
  const int plane = blockIdx.x;
  const int tid = threadIdx.x;
  {
    *(float4*)&Yl[tid * 4] = *(const float4*)&Y[(size_t)plane * 1024 + tid * 4];
  }
  __syncthreads();

  // ---- phase A: thread = (g 0..1 ky-half, h 0..127) ----
  {
    const int g = tid >> 7;
    const int h = tid & 127;
    float zr[8] = {}, zi[8] = {};
    float uw, uwi;   // U = e^{+2pi i h/128}
    __sincosf(PI2 * (float)h / 128.f, &uwi, &uw);
    const float4* Yl4 = (const float4*)Yl;
    // run 1: kxi 0..15 (kx=0..15), T starts at 1
    float Tr = 1.f, Ti = 0.f;
    #pragma unroll 4
    for (int kxi = 0; kxi < 16; ++kxi) {
      #pragma unroll
      for (int q = 0; q < 4; ++q) {
        float4 p = Yl4[kxi * 8 + g * 4 + q];
        int m = 2 * q;
        zr[m]   = fmaf(p.x, Tr, zr[m]);   zr[m]   = fmaf(-p.y, Ti, zr[m]);
        zi[m]   = fmaf(p.x, Ti, zi[m]);   zi[m]   = fmaf(p.y, Tr, zi[m]);
        zr[m+1] = fmaf(p.z, Tr, zr[m+1]); zr[m+1] = fmaf(-p.w, Ti, zr[m+1]);
        zi[m+1] = fmaf(p.z, Ti, zi[m+1]); zi[m+1] = fmaf(p.w, Tr, zi[m+1]);
      }
      float nr = Tr * uw - Ti * uwi, ni = Tr * uwi + Ti * uw;
      Tr = nr; Ti = ni;
    }
    // run 2: kxi 16..31 (kx=112..127), T starts at e^{+2pi i 112 h/128}
    __sincosf(PI2 * (float)((112 * h) & 127) / 128.f, &Ti, &Tr);
    #pragma unroll 4
    for (int kxi = 16; kxi < 32; ++kxi) {
      #pragma unroll
      for (int q = 0; q < 4; ++q) {
        float4 p = Yl4[kxi * 8 + g * 4 + q];
        int m = 2 * q;
        zr[m]   = fmaf(p.x, Tr, zr[m]);   zr[m]   = fmaf(-p.y, Ti, zr[m]);
        zi[m]   = fmaf(p.x, Ti, zi[m]);   zi[m]   = fmaf(p.y, Tr, zi[m]);
        zr[m+1] = fmaf(p.z, Tr, zr[m+1]); zr[m+1] = fmaf(-p.w, Ti, zr[m+1]);
        zi[m+1] = fmaf(p.z, Ti, zi[m+1]); zi[m+1] = fmaf(p.w, Tr, zi[m+1]);
      }
      float nr = Tr * uw - Ti * uwi, ni = Tr * uwi + Ti * uw;
      Tr = nr; Ti = ni;
    }
    #pragma unroll
    for (int m = 0; m < 8; ++m) {
      int ky = g * 8 + m;
      float f = (ky == 0) ? 1.f : 2.f;
      *(float2*)&Mt[(ky * 128 + h) * 2] = make_float2(f * zr[m], -f * zi[m]);
    }
  }
  __syncthreads();

  // ---- phase B: thread = (hq 0..3, w 0..63); 32 h each, outputs w and w+64 ----
  {
    const int hq = tid >> 6;
    const int w = tid & 63;
    float C[16], S[16];
    {
      float cw, sw;
      __sincosf(PI2 * (float)w / 128.f, &sw, &cw);
      C[0] = 1.f; S[0] = 0.f;
      #pragma unroll
      for (int k = 1; k < 16; ++k) {
        C[k] = C[k - 1] * cw - S[k - 1] * sw;
        S[k] = C[k - 1] * sw + S[k - 1] * cw;
      }
    }
    float* op = out + (size_t)plane * (128 * 128);
    const float2* Mt2 = (const float2*)Mt;
    for (int hj = 0; hj < 32; ++hj) {
      int h = hq * 32 + hj;
      float e = 0.f, o = 0.f;
      #pragma unroll
      for (int j2 = 0; j2 < 8; ++j2) {
        float2 m0 = Mt2[(2 * j2) * 128 + h];       // (Mc,Ms) for ky=2j2
        float2 m1 = Mt2[(2 * j2 + 1) * 128 + h];   // (Mc,Ms) for ky=2j2+1
        int k = 2 * j2;
        float t0 = m0.x * C[k] + m0.y * S[k];
        float t1 = m1.x * C[k + 1] + m1.y * S[k + 1];
        e += t0; o += t1;
      }
      op[h * 128 + w]      = e + o;
      op[h * 128 + w + 64] = e - o;
    }
  }
}

extern "C" void kernel_launch(void* const* d_in, const int* in_sizes, int n_in,
                              void* d_out, int out_size, void* d_ws, size_t ws_size,
                              hipStream_t stream) {
  const float* X   = (const float*)d_in[0];
  const float* w0r = (const float*)d_in[1];
  const float* w0i = (const float*)d_in[2];
  const float* w1r = (const float*)d_in[3];
  const float* w1i = (const float*)d_in[4];
  float* outp = (float*)d_out;
  float* Xf = (float*)d_ws;                  // 4 MB
  float* Yw = (float*)d_ws + (1u << 20);     // 4 MB
  k_fwd<<<1024, 256, 0, stream>>>(X, Xf);
  k_mix<<<1024, 256, 0, stream>>>(Xf, w0r, w0i, w1r, w1i, Yw);
  k_inv<<<1024, 256, 0, stream>>>(Yw, outp);
}

// Round 2
// 165.652 us; speedup vs baseline: 1.1072x; 1.1002x over previous
//
#include <hip/hip_runtime.h>

#define PI2 6.28318530717958647692f

// ===========================================================================
// Kernel 1: per (b,t) plane forward DFT restricted to kept modes.
// Conjugate symmetry: X real => A2[128-kx][w] = conj(A2[kx][w]), so phase 1
// computes only kx = 0..16 (17 rows). Phase 2 derives kxi>=16 by conjugation.
// Phase 1: thread = (w2 0..63, kxq 0..3); handles w in {w2, w2+64} and the
//   4 twiddled kx of slot group kxq (slot0 = kx16, slot k = kx k for 1..15;
//   every group's slots alternate even,odd parity). kxq0 also does DC (kx=0).
//   Twiddle reads: 2 ds_read_b128 per h-iter per wave (was 8).
// Phase 2: thread = (kxi 0..31, t 0..7); ky = {t,t+8}; ky-twiddles held in
//   registers, advanced by complex step, exact refresh at w=32. No E2 table.
// A2t: [w][row 0..16, stride 18] f2 (18.4 KB). Tt: [h<64][slot<16] f2 (8 KB).
// Xf layout: [plane][kxi][ky][ri] (1024 dwords/plane). Scale 1/16384.
// ===========================================================================
__global__ __launch_bounds__(256, 4) void k_fwd(const float* __restrict__ X,
                                                float* __restrict__ Xf) {
  __shared__ __attribute__((aligned(16))) float A2t[128 * 18 * 2];  // 18.4 KB
  __shared__ __attribute__((aligned(16))) float Tt[64 * 16 * 2];    // 8 KB
  const int plane = blockIdx.x;
  const int tid = threadIdx.x;
  const float* Xp = X + (size_t)plane * (128 * 128);

  // ---- E1 table: Tt[h][slot]: slot0 -> kx=16, slot k -> kx=k (1..15) ----
  #pragma unroll
  for (int k = 0; k < 4; ++k) {
    int idx = tid + k * 256;              // 1024 entries
    int h = idx >> 4, slot = idx & 15;
    int kx = slot ? slot : 16;
    float ang = -PI2 * (float)((kx * h) & 127) / 128.f;
    float s_, c_;
    __sincosf(ang, &s_, &c_);
    Tt[idx * 2] = c_; Tt[idx * 2 + 1] = s_;
  }
  __syncthreads();

  // ---- phase 1 ----
  {
    const int w2 = tid & 63;
    const int kxq = tid >> 6;             // wave-uniform
    float ar[4][2], ai[4][2];             // [slot j][w-sel]
    #pragma unroll
    for (int j = 0; j < 4; ++j) {
      ar[j][0] = 0.f; ar[j][1] = 0.f; ai[j][0] = 0.f; ai[j][1] = 0.f;
    }
    float dcA = 0.f, dcB = 0.f;
    float x0a = Xp[w2],      x1a = Xp[64 * 128 + w2];
    float x0b = Xp[w2 + 64], x1b = Xp[64 * 128 + w2 + 64];
    for (int h = 0; h < 64; ++h) {
      float n0a = 0.f, n1a = 0.f, n0b = 0.f, n1b = 0.f;
      if (h < 63) {
        n0a = Xp[(h + 1) * 128 + w2];      n1a = Xp[(h + 65) * 128 + w2];
        n0b = Xp[(h + 1) * 128 + w2 + 64]; n1b = Xp[(h + 65) * 128 + w2 + 64];
      }
      float uea = x0a + x1a, uoa = x0a - x1a;
      float ueb = x0b + x1b, uob = x0b - x1b;
      const float4* Trow = (const float4*)&Tt[h * 32];
      float4 e01 = Trow[kxq * 2];         // slots 4q, 4q+1 (even, odd kx)
      float4 e23 = Trow[kxq * 2 + 1];     // slots 4q+2, 4q+3 (even, odd kx)
      ar[0][0] = fmaf(uea, e01.x, ar[0][0]); ai[0][0] = fmaf(uea, e01.y, ai[0][0]);
      ar[0][1] = fmaf(ueb, e01.x, ar[0][1]); ai[0][1] = fmaf(ueb, e01.y, ai[0][1]);
      ar[1][0] = fmaf(uoa, e01.z, ar[1][0]); ai[1][0] = fmaf(uoa, e01.w, ai[1][0]);
      ar[1][1] = fmaf(uob, e01.z, ar[1][1]); ai[1][1] = fmaf(uob, e01.w, ai[1][1]);
      ar[2][0] = fmaf(uea, e23.x, ar[2][0]); ai[2][0] = fmaf(uea, e23.y, ai[2][0]);
      ar[2][1] = fmaf(ueb, e23.x, ar[2][1]); ai[2][1] = fmaf(ueb, e23.y, ai[2][1]);
      ar[3][0] = fmaf(uoa, e23.z, ar[3][0]); ai[3][0] = fmaf(uoa, e23.w, ai[3][0]);
      ar[3][1] = fmaf(uob, e23.z, ar[3][1]); ai[3][1] = fmaf(uob, e23.w, ai[3][1]);
      if (kxq == 0) { dcA += uea; dcB += ueb; }   // wave-uniform branch
      x0a = n0a; x1a = n1a; x0b = n0b; x1b = n1b;
    }
    #pragma unroll
    for (int j = 0; j < 4; ++j) {
      int s = kxq * 4 + j;
      int row = (s == 0) ? 16 : s;
      *(float2*)&A2t[(w2 * 18 + row) * 2]        = make_float2(ar[j][0], ai[j][0]);
      *(float2*)&A2t[((w2 + 64) * 18 + row) * 2] = make_float2(ar[j][1], ai[j][1]);
    }
    if (kxq == 0) {
      *(float2*)&A2t[(w2 * 18) * 2]        = make_float2(dcA, 0.f);
      *(float2*)&A2t[((w2 + 64) * 18) * 2] = make_float2(dcB, 0.f);
    }
  }
  __syncthreads();

  // ---- phase 2: thread = (kxi 0..31, t 0..7); ky = {t, t+8} ----
  {
    const int kxi = tid >> 3;
    const int t = tid & 7;
    const int row = (kxi < 16) ? kxi : (32 - kxi);
    const float csign = (kxi < 16) ? 1.f : -1.f;   // conj for kxi>=16
    const float s = (t & 1) ? -1.f : 1.f;          // (-1)^ky
    float s0r, s0i, s1r, s1i;
    __sincosf(-PI2 * (float)t / 128.f, &s0i, &s0r);
    __sincosf(-PI2 * (float)(t + 8) / 128.f, &s1i, &s1r);
    float r0 = 0.f, i0 = 0.f, r1 = 0.f, i1 = 0.f;
    float E0r = 1.f, E0i = 0.f, E1r = 1.f, E1i = 0.f;
    #pragma unroll
    for (int half = 0; half < 2; ++half) {
      if (half == 1) {   // exact refresh: e^{-i pi t/2} == e^{-i pi (t+8)/2}
        float c_, s_;
        __sincosf(-1.57079632679489662f * (float)t, &s_, &c_);
        E0r = c_; E0i = s_; E1r = c_; E1i = s_;
      }
      for (int w = half * 32; w < half * 32 + 32; ++w) {
        float2 a = *(const float2*)&A2t[(w * 18 + row) * 2];
        float2 b = *(const float2*)&A2t[((w + 64) * 18 + row) * 2];
        float ur = fmaf(s, b.x, a.x);
        float ui = csign * fmaf(s, b.y, a.y);
        r0 = fmaf(ur, E0r, r0); r0 = fmaf(-ui, E0i, r0);
        i0 = fmaf(ur, E0i, i0); i0 = fmaf(ui, E0r, i0);
        r1 = fmaf(ur, E1r, r1); r1 = fmaf(-ui, E1i, r1);
        i1 = fmaf(ur, E1i, i1); i1 = fmaf(ui, E1r, i1);
        float u0 = E0r * s0r - E0i * s0i; E0i = E0r * s0i + E0i * s0r; E0r = u0;
        float u1 = E1r * s1r - E1i * s1i; E1i = E1r * s1i + E1i * s1r; E1r = u1;
      }
    }
    const float sc = 1.f / 16384.f;
    float* base = Xf + (size_t)plane * 1024 + kxi * 32;
    *(float2*)&base[t * 2]       = make_float2(r0 * sc, i0 * sc);
    *(float2*)&base[(t + 8) * 2] = make_float2(r1 * sc, i1 * sc);
  }
}

// ===========================================================================
// Kernel 2: channel mix. block = (corner 2, x 16, cg 16), c-tile of 4.
// grid 512. Weights packed (t even, t odd) per float4 -> b128 LDS reads.
// thread = (b 16, y 16). Y[b][c][kxi][ky][ri], same layout as Xf.
// ===========================================================================
__global__ __launch_bounds__(256, 2) void k_mix(const float* __restrict__ Xf,
                                                const float* __restrict__ w0r,
                                                const float* __restrict__ w0i,
                                                const float* __restrict__ w1r,
                                                const float* __restrict__ w1i,
                                                float* __restrict__ Y) {
  __shared__ __attribute__((aligned(16))) float Wl[4 * 32 * 16 * 4]; // 32 KB
  const int bid = blockIdx.x;               // 0..511
  const int c2 = bid >> 8;
  const int x  = (bid >> 4) & 15;
  const int cg = bid & 15;
  const int c0 = cg * 4;
  const int kxi = c2 * 16 + x;
  const float* Wr_g = c2 ? w1r : w0r;
  const float* Wi_g = c2 ? w1i : w0i;
  const int tid = threadIdx.x;
  const int b = tid >> 4;
  const int y = tid & 15;

  // stage: 4096 complex; Wl f4[(c*32 + t/2)*16 + y] = (wr_e, wi_e, wr_o, wi_o)
  #pragma unroll
  for (int k = 0; k < 16; ++k) {
    int idx = tid + k * 256;                // 0..4095
    int y_ = idx & 15, t_ = (idx >> 4) & 63, c_ = idx >> 10;
    size_t ga = (((size_t)(c0 + c_) * 64 + t_) * 16 + x) * 16 + y_;
    int f2i = ((c_ * 32 + (t_ >> 1)) * 16 + y_) * 2 + (t_ & 1);
    *(float2*)&Wl[f2i * 2] = make_float2(Wr_g[ga], Wi_g[ga]);
  }
  __syncthreads();

  float aR[4] = {}, aI[4] = {};
  const float* xbase = Xf + ((size_t)b * 64) * 1024 + kxi * 32 + y * 2;
  for (int t8 = 0; t8 < 64; t8 += 8) {
    float2 xv[8];
    #pragma unroll
    for (int q = 0; q < 8; ++q)
      xv[q] = *(const float2*)&xbase[(size_t)(t8 + q) * 1024];
    #pragma unroll
    for (int p = 0; p < 4; ++p) {           // t2 pair index
      int t2 = (t8 >> 1) + p;
      float2 xe = xv[2 * p], xo = xv[2 * p + 1];
      #pragma unroll
      for (int cj = 0; cj < 4; ++cj) {
        float4 wv = *(const float4*)&Wl[((cj * 32 + t2) * 16 + y) * 4];
        aR[cj] = fmaf(xe.x, wv.x, aR[cj]); aR[cj] = fmaf(-xe.y, wv.y, aR[cj]);
        aI[cj] = fmaf(xe.x, wv.y, aI[cj]); aI[cj] = fmaf(xe.y, wv.x, aI[cj]);
        aR[cj] = fmaf(xo.x, wv.z, aR[cj]); aR[cj] = fmaf(-xo.y, wv.w, aR[cj]);
        aI[cj] = fmaf(xo.x, wv.w, aI[cj]); aI[cj] = fmaf(xo.y, wv.z, aI[cj]);
      }
    }
  }
  #pragma unroll
  for (int cj = 0; cj < 4; ++cj) {
    size_t ya = ((size_t)(b * 64 + c0 + cj)) * 1024 + kxi * 32 + y * 2;
    *(float2*)&Y[ya] = make_float2(aR[cj], aI[cj]);
  }
}

// ===========================================================================
// Kernel 3: per (b,c) plane inverse.
// Phase A: thread = (g 0..3 ky-quad, h2 0..63); handles h in {h2, h2+64}
//   via sign (-1)^kx on the shared twiddle. Stores Mt f4-packed with XOR
//   swizzle: f4idx = h*8 + (j ^ (h&7))  (write-conflict-free).
// Phase B: thread = (hp 0..7, w2 0..31); 16 h each, outputs w2, w2+32,
//   w2+64, w2+96. The w2+32 twiddles are the i^k register rotation of w2's
//   C/S; the +64 fold uses ky parity. Mt reads: 8 b128 per h (2-addr bcast).
// ===========================================================================
__global__ __launch_bounds__(256, 4) void k_inv(const float* __restrict__ Y,
                                                float* __restrict__ out) {
  __shared__ __attribute__((aligned(16))) float Yl[1024];
  __shared__ __attribute__((aligned(16))) float Mt[128 * 16 * 2];  // 16 KB
  const int plane = blockIdx.x;
  const int tid = threadIdx.x;
  *(float4*)&Yl[tid * 4] = *(const float4*)&Y[(size_t)plane * 1024 + tid * 4];
  __syncthreads();

  // ---- phase A ----
  {
    const int g = tid >> 6;          // ky quad: ky = 4g..4g+3 (wave-uniform)
    const int h2 = tid & 63;
    float zr[2][4] = {}, zi[2][4] = {};   // [h-sel][ky j]
    float uw, uwi;                   // U = e^{+2pi i h2/128}
    __sincosf(PI2 * (float)h2 / 128.f, &uwi, &uw);
    const float4* Yl4 = (const float4*)Yl;
    float Tr = 1.f, Ti = 0.f;
    #pragma unroll 2
    for (int kxi = 0; kxi < 16; ++kxi) {
      float sgn = (kxi & 1) ? -1.f : 1.f;    // (-1)^kx for h2+64
      #pragma unroll
      for (int q = 0; q < 2; ++q) {
        float4 p = Yl4[kxi * 8 + g * 2 + q];
        float cr0 = p.x * Tr - p.y * Ti, ci0 = p.x * Ti + p.y * Tr;
        float cr1 = p.z * Tr - p.w * Ti, ci1 = p.z * Ti + p.w * Tr;
        zr[0][2*q]   += cr0; zi[0][2*q]   += ci0;
        zr[0][2*q+1] += cr1; zi[0][2*q+1] += ci1;
        zr[1][2*q]   = fmaf(sgn, cr0, zr[1][2*q]);   zi[1][2*q]   = fmaf(sgn, ci0, zi[1][2*q]);
        zr[1][2*q+1] = fmaf(sgn, cr1, zr[1][2*q+1]); zi[1][2*q+1] = fmaf(sgn, ci1, zi[1][2*q+1]);
      }
      float nr = Tr * uw - Ti * uwi, ni = Tr * uwi + Ti * uw;
      Tr = nr; Ti = ni;
    }
    __sincosf(PI2 * (float)((112 * h2) & 127) / 128.f, &Ti, &Tr);
    #pragma unroll 2
    for (int kxi = 16; kxi < 32; ++kxi) {
      float sgn = (kxi & 1) ? -1.f : 1.f;
      #pragma unroll
      for (int q = 0; q < 2; ++q) {
        float4 p = Yl4[kxi * 8 + g * 2 + q];
        float cr0 = p.x * Tr - p.y * Ti, ci0 = p.x * Ti + p.y * Tr;
        float cr1 = p.z * Tr - p.w * Ti, ci1 = p.z * Ti + p.w * Tr;
        zr[0][2*q]   += cr0; zi[0][2*q]   += ci0;
        zr[0][2*q+1] += cr1; zi[0][2*q+1] += ci1;
        zr[1][2*q]   = fmaf(sgn, cr0, zr[1][2*q]);   zi[1][2*q]   = fmaf(sgn, ci0, zi[1][2*q]);
        zr[1][2*q+1] = fmaf(sgn, cr1, zr[1][2*q+1]); zi[1][2*q+1] = fmaf(sgn, ci1, zi[1][2*q+1]);
      }
      float nr = Tr * uw - Ti * uwi, ni = Tr * uwi + Ti * uw;
      Tr = nr; Ti = ni;
    }
    #pragma unroll
    for (int hs = 0; hs < 2; ++hs) {
      int h = h2 + hs * 64;
      #pragma unroll
      for (int q = 0; q < 2; ++q) {
        int ky0 = g * 4 + 2 * q;
        float f0 = (ky0 == 0) ? 1.f : 2.f;
        float4 v = make_float4(f0 * zr[hs][2*q],   -f0 * zi[hs][2*q],
                               2.f * zr[hs][2*q+1], -2.f * zi[hs][2*q+1]);
        int f4i = h * 8 + ((g * 2 + q) ^ (h & 7));
        *(float4*)&Mt[f4i * 4] = v;
      }
    }
  }
  __syncthreads();

  // ---- phase B ----
  {
    const int hp = tid >> 5;        // 0..7
    const int w2 = tid & 31;        // 0..31
    float C[16], S[16];
    {
      float cw, sw;
      __sincosf(PI2 * (float)w2 / 128.f, &sw, &cw);
      C[0] = 1.f; S[0] = 0.f;
      #pragma unroll
      for (int k = 1; k < 16; ++k) {
        C[k] = C[k - 1] * cw - S[k - 1] * sw;
        S[k] = C[k - 1] * sw + S[k - 1] * cw;
      }
    }
    float* op = out + (size_t)plane * (128 * 128);
    const float4* Mt4 = (const float4*)Mt;
    #pragma unroll 2
    for (int hj = 0; hj < 16; ++hj) {
      int h = hp * 16 + hj;
      float e = 0.f, o = 0.f, e2 = 0.f, o2 = 0.f;
      #pragma unroll
      for (int j = 0; j < 8; ++j) {
        float4 m = Mt4[h * 8 + (j ^ (h & 7))];   // (Mc,Ms) ky=2j | ky=2j+1
        int k0 = 2 * j, k1 = 2 * j + 1;
        e = fmaf(m.x, C[k0], e); e = fmaf(m.y, S[k0], e);
        o = fmaf(m.z, C[k1], o); o = fmaf(m.w, S[k1], o);
        // w2+32: cos(th+pi k/2), sin(th+pi k/2) rotations
        if ((k0 & 2) == 0) { e2 = fmaf(m.x, C[k0], e2); e2 = fmaf(m.y, S[k0], e2); }
        else               { e2 = fmaf(-m.x, C[k0], e2); e2 = fmaf(-m.y, S[k0], e2); }
        if ((k1 & 2) == 0) { o2 = fmaf(m.w, C[k1], o2); o2 = fmaf(-m.z, S[k1], o2); }
        else               { o2 = fmaf(-m.w, C[k1], o2); o2 = fmaf(m.z, S[k1], o2); }
      }
      op[h * 128 + w2]      = e + o;
      op[h * 128 + w2 + 64] = e - o;
      op[h * 128 + w2 + 32] = e2 + o2;
      op[h * 128 + w2 + 96] = e2 - o2;
    }
  }
}

extern "C" void kernel_launch(void* const* d_in, const int* in_sizes, int n_in,
                              void* d_out, int out_size, void* d_ws, size_t ws_size,
                              hipStream_t stream) {
  const float* X   = (const float*)d_in[0];
  const float* w0r = (const float*)d_in[1];
  const float* w0i = (const float*)d_in[2];
  const float* w1r = (const float*)d_in[3];
  const float* w1i = (const float*)d_in[4];
  float* outp = (float*)d_out;
  float* Xf = (float*)d_ws;                  // 4 MB
  float* Yw = (float*)d_ws + (1u << 20);     // 4 MB
  k_fwd<<<1024, 256, 0, stream>>>(X, Xf);
  k_mix<<<512, 256, 0, stream>>>(Xf, w0r, w0i, w1r, w1i, Yw);
  k_inv<<<1024, 256, 0, stream>>>(Yw, outp);
}